// Round 2
// baseline (22721.306 us; speedup 1.0000x reference)
//
#include <hip/hip_runtime.h>
#include <hip/hip_bf16.h>

#define T 2048
#define C 4096
#define H 32
#define KVH 8
#define D 128
// rep = H/KVH = 4

// C[M,N] = A[M,K] @ B[K,N], all fp32 row-major.
// BM=BN=64, BK=16, 256 threads, 4x4 per thread. M,N,K multiples of 64/16.
__global__ __launch_bounds__(256) void gemm_f32(
    const float* __restrict__ A,
    const float* __restrict__ B,
    float* __restrict__ Cm, int M, int N, int K) {
  const int BM = 64, BN = 64, BK = 16;
  __shared__ float As[BK][BM + 1];
  __shared__ float Bs[BK][BN + 1];
  const int tx = threadIdx.x % 16;
  const int ty = threadIdx.x / 16;
  const int row0 = blockIdx.y * BM;
  const int col0 = blockIdx.x * BN;
  float c[4][4] = {};
  for (int k0 = 0; k0 < K; k0 += BK) {
    for (int i = threadIdx.x; i < BM * BK; i += 256) {
      int r = i / BK, cc = i % BK;
      As[cc][r] = A[(size_t)(row0 + r) * K + k0 + cc];
    }
    for (int i = threadIdx.x; i < BK * BN; i += 256) {
      int r = i / BN, cc = i % BN;
      Bs[r][cc] = B[(size_t)(k0 + r) * N + col0 + cc];
    }
    __syncthreads();
#pragma unroll
    for (int kk = 0; kk < BK; ++kk) {
      float a[4], b[4];
#pragma unroll
      for (int i = 0; i < 4; ++i) a[i] = As[kk][ty * 4 + i];
#pragma unroll
      for (int j = 0; j < 4; ++j) b[j] = Bs[kk][tx * 4 + j];
#pragma unroll
      for (int i = 0; i < 4; ++i)
#pragma unroll
        for (int j = 0; j < 4; ++j) c[i][j] += a[i] * b[j];
    }
    __syncthreads();
  }
#pragma unroll
  for (int i = 0; i < 4; ++i)
#pragma unroll
    for (int j = 0; j < 4; ++j) {
      int r = row0 + ty * 4 + i, cc = col0 + tx * 4 + j;
      Cm[(size_t)r * N + cc] = c[i][j];
    }
}

// In-place RoPE on q (T x H*D) and k (T x KVH*D). One thread per (t, head, d<64).
__global__ __launch_bounds__(256) void rope_kernel(
    float* __restrict__ q, float* __restrict__ k,
    const float* __restrict__ cosb,
    const float* __restrict__ sinb) {
  int idx = blockIdx.x * 256 + threadIdx.x;
  int total = T * (H + KVH) * (D / 2);
  if (idx >= total) return;
  int d = idx % (D / 2);
  int rest = idx / (D / 2);
  int head = rest % (H + KVH);
  int t = rest / (H + KVH);
  float cv = cosb[(size_t)t * D + d];   // cos table duplicated across halves
  float sv = sinb[(size_t)t * D + d];
  float* base;
  if (head < H) base = q + (size_t)t * (H * D) + head * D;
  else          base = k + (size_t)t * (KVH * D) + (head - H) * D;
  float u1 = base[d];
  float u2 = base[d + D / 2];
  base[d]         = u1 * cv - u2 * sv;  // u*cos + rotate_half(u)*sin, first half
  base[d + D / 2] = u2 * cv + u1 * sv;  // second half
}

// out_k[h][t][d] = k[t][h*D+d] (post-RoPE), out_v likewise. fp32 out.
__global__ __launch_bounds__(256) void write_kv(
    const float* __restrict__ k, const float* __restrict__ v,
    float* __restrict__ outk, float* __restrict__ outv) {
  int idx = blockIdx.x * 256 + threadIdx.x;
  if (idx >= KVH * T * D) return;
  int d = idx % D;
  int t = (idx / D) % T;
  int h = idx / (D * T);
  size_t src = (size_t)t * (KVH * D) + h * D + d;
  outk[idx] = k[src];
  outv[idx] = v[src];
}

// One workgroup per (query row r, head h). Scores for j<=r in LDS, exact softmax.
// Masked (j>r) entries contribute exp(-40000-m)=0 exactly in fp32, so skipping
// them is equivalent to the additive-mask reference; the mask tensor is unused.
// Output written IN-PLACE over q: block (r,h) reads exactly the 128 q elements
// it later overwrites (no cross-block overlap), so this is race-free.
__global__ __launch_bounds__(256) void attn_kernel(
    float* __restrict__ q, const float* __restrict__ k,
    const float* __restrict__ v) {
  __shared__ float s[T];
  __shared__ float qs[D];
  __shared__ float red[256];
  const int r = blockIdx.x;
  const int h = blockIdx.y;
  const int kvh = h >> 2;
  const int tid = threadIdx.x;
  if (tid < D) qs[tid] = q[(size_t)r * C + h * D + tid];
  __syncthreads();
  const int n = r + 1;
  // scores s[j] = q . k_j
  for (int j = tid; j < n; j += 256) {
    const float4* kr = (const float4*)(k + (size_t)j * (KVH * D) + kvh * D);
    float acc = 0.f;
#pragma unroll
    for (int d4 = 0; d4 < D / 4; ++d4) {
      float4 kk = kr[d4];
      acc += kk.x * qs[d4 * 4 + 0] + kk.y * qs[d4 * 4 + 1] +
             kk.z * qs[d4 * 4 + 2] + kk.w * qs[d4 * 4 + 3];
    }
    s[j] = acc;
  }
  __syncthreads();
  // max
  float m = -INFINITY;
  for (int j = tid; j < n; j += 256) m = fmaxf(m, s[j]);
  red[tid] = m;
  __syncthreads();
  for (int off = 128; off > 0; off >>= 1) {
    if (tid < off) red[tid] = fmaxf(red[tid], red[tid + off]);
    __syncthreads();
  }
  m = red[0];
  __syncthreads();
  // exp + sum
  float sum = 0.f;
  for (int j = tid; j < n; j += 256) {
    float p = __expf(s[j] - m);
    s[j] = p;
    sum += p;
  }
  red[tid] = sum;
  __syncthreads();
  for (int off = 128; off > 0; off >>= 1) {
    if (tid < off) red[tid] += red[tid + off];
    __syncthreads();
  }
  float inv = 1.0f / red[0];
  __syncthreads();
  // y[d] = inv * sum_j p[j] * v[j][d]; two halves over j parity
  const int d = tid & 127;
  const int half = tid >> 7;
  float acc = 0.f;
  for (int j = half; j < n; j += 2)
    acc += s[j] * v[(size_t)j * (KVH * D) + kvh * D + d];
  __syncthreads();
  red[tid] = acc;
  __syncthreads();
  if (half == 0) {
    float y = (red[tid] + red[tid + 128]) * inv;
    q[(size_t)r * C + h * D + d] = y;   // overwrite q with attention output
  }
}

extern "C" void kernel_launch(void* const* d_in, const int* in_sizes, int n_in,
                              void* d_out, int out_size, void* d_ws, size_t ws_size,
                              hipStream_t stream) {
  (void)in_sizes; (void)n_in; (void)out_size; (void)ws_size;
  const float* x    = (const float*)d_in[0];
  const float* Wq   = (const float*)d_in[1];
  const float* Wk   = (const float*)d_in[2];
  const float* Wv   = (const float*)d_in[3];
  const float* Wo   = (const float*)d_in[4];
  const float* cosb = (const float*)d_in[5];
  const float* sinb = (const float*)d_in[6];
  // d_in[7] = mask: unused (causal structure applied exactly)

  // workspace layout (48 MB total)
  float* q_ws = (float*)d_ws;                        // T*C fp32 (q, then y_att in-place)
  float* k_ws = q_ws + (size_t)T * C;                // T*KVH*D fp32
  float* v_ws = k_ws + (size_t)T * KVH * D;          // T*KVH*D fp32

  float* out_y = (float*)d_out;
  float* out_k = out_y + (size_t)T * C;
  float* out_v = out_k + (size_t)KVH * T * D;

  dim3 blk(256);
  // projections
  gemm_f32<<<dim3(C / 64, T / 64), blk, 0, stream>>>(x, Wq, q_ws, T, C, C);
  gemm_f32<<<dim3((KVH * D) / 64, T / 64), blk, 0, stream>>>(x, Wk, k_ws, T, KVH * D, C);
  gemm_f32<<<dim3((KVH * D) / 64, T / 64), blk, 0, stream>>>(x, Wv, v_ws, T, KVH * D, C);
  // rope on q and k
  int rope_total = T * (H + KVH) * (D / 2);
  rope_kernel<<<(rope_total + 255) / 256, blk, 0, stream>>>(q_ws, k_ws, cosb, sinb);
  // kv outputs (post-rope k, raw v), transposed to (KVH,T,D)
  write_kv<<<(KVH * T * D + 255) / 256, blk, 0, stream>>>(k_ws, v_ws, out_k, out_v);
  // attention (writes y_att over q_ws)
  attn_kernel<<<dim3(T, H), blk, 0, stream>>>(q_ws, k_ws, v_ws);
  // output projection
  gemm_f32<<<dim3(C / 64, T / 64), blk, 0, stream>>>(q_ws, Wo, out_y, T, C, C);
}

// Round 3
// 6110.809 us; speedup vs baseline: 3.7182x; 3.7182x over previous
//
#include <hip/hip_runtime.h>
#include <hip/hip_bf16.h>

#define T 2048
#define C 4096
#define H 32
#define KVH 8
#define D 128
// rep = H/KVH = 4

typedef __bf16 bf16x8 __attribute__((ext_vector_type(8)));
typedef float floatx4 __attribute__((ext_vector_type(4)));

// ---------------- fp32 tiled GEMM (unchanged from round 2) ----------------
__global__ __launch_bounds__(256) void gemm_f32(
    const float* __restrict__ A,
    const float* __restrict__ B,
    float* __restrict__ Cm, int M, int N, int K) {
  const int BM = 64, BN = 64, BK = 16;
  __shared__ float As[BK][BM + 1];
  __shared__ float Bs[BK][BN + 1];
  const int tx = threadIdx.x % 16;
  const int ty = threadIdx.x / 16;
  const int row0 = blockIdx.y * BM;
  const int col0 = blockIdx.x * BN;
  float c[4][4] = {};
  for (int k0 = 0; k0 < K; k0 += BK) {
    for (int i = threadIdx.x; i < BM * BK; i += 256) {
      int r = i / BK, cc = i % BK;
      As[cc][r] = A[(size_t)(row0 + r) * K + k0 + cc];
    }
    for (int i = threadIdx.x; i < BK * BN; i += 256) {
      int r = i / BN, cc = i % BN;
      Bs[r][cc] = B[(size_t)(k0 + r) * N + col0 + cc];
    }
    __syncthreads();
#pragma unroll
    for (int kk = 0; kk < BK; ++kk) {
      float a[4], b[4];
#pragma unroll
      for (int i = 0; i < 4; ++i) a[i] = As[kk][ty * 4 + i];
#pragma unroll
      for (int j = 0; j < 4; ++j) b[j] = Bs[kk][tx * 4 + j];
#pragma unroll
      for (int i = 0; i < 4; ++i)
#pragma unroll
        for (int j = 0; j < 4; ++j) c[i][j] += a[i] * b[j];
    }
    __syncthreads();
  }
#pragma unroll
  for (int i = 0; i < 4; ++i)
#pragma unroll
    for (int j = 0; j < 4; ++j) {
      int r = row0 + ty * 4 + i, cc = col0 + tx * 4 + j;
      Cm[(size_t)r * N + cc] = c[i][j];
    }
}

// ---------------- RoPE in-place on q (T x H*D) and k (T x KVH*D) ----------
__global__ __launch_bounds__(256) void rope_kernel(
    float* __restrict__ q, float* __restrict__ k,
    const float* __restrict__ cosb,
    const float* __restrict__ sinb) {
  int idx = blockIdx.x * 256 + threadIdx.x;
  int total = T * (H + KVH) * (D / 2);
  if (idx >= total) return;
  int d = idx % (D / 2);
  int rest = idx / (D / 2);
  int head = rest % (H + KVH);
  int t = rest / (H + KVH);
  float cv = cosb[(size_t)t * D + d];
  float sv = sinb[(size_t)t * D + d];
  float* base;
  if (head < H) base = q + (size_t)t * (H * D) + head * D;
  else          base = k + (size_t)t * (KVH * D) + (head - H) * D;
  float u1 = base[d];
  float u2 = base[d + D / 2];
  base[d]         = u1 * cv - u2 * sv;
  base[d + D / 2] = u2 * cv + u1 * sv;
}

// ---- k: emit out_k (fp32 [kvh][t][d]) + khi/klo (bf16 split, same layout) ----
__global__ __launch_bounds__(256) void convert_k(
    const float* __restrict__ k_ws, float* __restrict__ out_k,
    __bf16* __restrict__ khi, __bf16* __restrict__ klo) {
  int idx = blockIdx.x * 256 + threadIdx.x;
  if (idx >= KVH * T * D) return;
  int d = idx & (D - 1);
  int t = (idx >> 7) & (T - 1);
  int kvh = idx >> 18;
  float f = k_ws[(size_t)t * (KVH * D) + kvh * D + d];
  out_k[idx] = f;                      // idx == ((kvh*T)+t)*D + d
  __bf16 hi = (__bf16)f;
  khi[idx] = hi;
  klo[idx] = (__bf16)(f - (float)hi);
}

// ---- v: emit out_v (fp32 [kvh][t][d]) + vt (bf16 transposed [kvh][d][t]) ----
__global__ __launch_bounds__(256) void convert_v(
    const float* __restrict__ v_ws, float* __restrict__ out_v,
    __bf16* __restrict__ vt) {
  __shared__ __bf16 tile[64][65];
  const int t0 = blockIdx.x * 64;
  const int d0 = blockIdx.y * 64;
  const int kvh = blockIdx.z;
#pragma unroll
  for (int p = 0; p < 16; ++p) {
    int i = p * 256 + threadIdx.x;
    int r = i >> 6;      // t offset
    int c = i & 63;      // d offset (consecutive tid -> coalesced)
    float f = v_ws[(size_t)(t0 + r) * (KVH * D) + kvh * D + d0 + c];
    out_v[((size_t)kvh * T + t0 + r) * D + d0 + c] = f;
    tile[r][c] = (__bf16)f;
  }
  __syncthreads();
#pragma unroll
  for (int p = 0; p < 16; ++p) {
    int i = p * 256 + threadIdx.x;
    int dd = i >> 6;     // d offset
    int tt = i & 63;     // t offset (consecutive tid -> coalesced)
    vt[((size_t)kvh * D + d0 + dd) * T + t0 + tt] = tile[tt][dd];
  }
}

// ---------------- MFMA flash attention, barrier-free -----------------------
// Grid (T/64, H); 256 threads = 4 independent waves; wave w owns q rows
// [bx*64 + w*16, +16) of head h. Split-precision bf16 QK^T (3 MFMAs / chunk),
// plain bf16 PV. Online softmax in registers; P goes C-layout -> A-layout via
// a per-wave LDS round-trip (DS ops are in-order per wave; no barrier).
// Masked cols use -inf; every processed tile has >=1 valid col per row since
// j0 <= r_base always. Output overwrites q in place (wave reads exactly the
// q elements it later writes; no cross-wave overlap).
__global__ __launch_bounds__(256) void flash_attn(
    float* __restrict__ q,
    const __bf16* __restrict__ khi,   // [KVH][T][D]
    const __bf16* __restrict__ klo,   // [KVH][T][D]
    const __bf16* __restrict__ vt) {  // [KVH][D][T]
  __shared__ __attribute__((aligned(16))) __bf16 Pst[4][16][40];
  const int tid = threadIdx.x;
  const int w = tid >> 6;
  const int lane = tid & 63;
  const int n16 = lane & 15;
  const int quad = lane >> 4;
  const int h = blockIdx.y;
  const int kvh = h >> 2;
  const int r_base = blockIdx.x * 64 + w * 16;

  // Q fragments, A-layout: lane holds row m = n16, k-dim d = c*32 + quad*8 + jj
  bf16x8 qhi[4], qlo[4];
  {
    const float* qrow = q + (size_t)(r_base + n16) * C + h * D;
#pragma unroll
    for (int c = 0; c < 4; ++c) {
      const float* p = qrow + c * 32 + quad * 8;
#pragma unroll
      for (int jj = 0; jj < 8; ++jj) {
        float f = p[jj];
        __bf16 hi = (__bf16)f;
        qhi[c][jj] = hi;
        qlo[c][jj] = (__bf16)(f - (float)hi);
      }
    }
  }

  floatx4 O[8];
#pragma unroll
  for (int dt = 0; dt < 8; ++dt) O[dt] = (floatx4){0.f, 0.f, 0.f, 0.f};
  float m_i[4] = {-INFINITY, -INFINITY, -INFINITY, -INFINITY};
  float l_i[4] = {0.f, 0.f, 0.f, 0.f};

  const __bf16* Kh = khi + (size_t)kvh * T * D;
  const __bf16* Kl = klo + (size_t)kvh * T * D;
  const __bf16* Vt = vt + (size_t)kvh * D * T;

  const int ntiles = (r_base + 15) / 32 + 1;
  for (int t = 0; t < ntiles; ++t) {
    const int j0 = t * 32;
    floatx4 s0 = {0.f, 0.f, 0.f, 0.f};
    floatx4 s1 = {0.f, 0.f, 0.f, 0.f};
#pragma unroll
    for (int c = 0; c < 4; ++c) {
      const size_t off = (size_t)c * 32 + quad * 8;
      bf16x8 k0h = *(const bf16x8*)(Kh + (size_t)(j0 + n16) * D + off);
      bf16x8 k0l = *(const bf16x8*)(Kl + (size_t)(j0 + n16) * D + off);
      bf16x8 k1h = *(const bf16x8*)(Kh + (size_t)(j0 + 16 + n16) * D + off);
      bf16x8 k1l = *(const bf16x8*)(Kl + (size_t)(j0 + 16 + n16) * D + off);
      s0 = __builtin_amdgcn_mfma_f32_16x16x32_bf16(qhi[c], k0h, s0, 0, 0, 0);
      s0 = __builtin_amdgcn_mfma_f32_16x16x32_bf16(qlo[c], k0h, s0, 0, 0, 0);
      s0 = __builtin_amdgcn_mfma_f32_16x16x32_bf16(qhi[c], k0l, s0, 0, 0, 0);
      s1 = __builtin_amdgcn_mfma_f32_16x16x32_bf16(qhi[c], k1h, s1, 0, 0, 0);
      s1 = __builtin_amdgcn_mfma_f32_16x16x32_bf16(qlo[c], k1h, s1, 0, 0, 0);
      s1 = __builtin_amdgcn_mfma_f32_16x16x32_bf16(qhi[c], k1l, s1, 0, 0, 0);
    }
    // causal mask (wave-uniform branch; C-layout rows r = r_base + quad*4 + i)
    if (j0 + 31 > r_base) {
#pragma unroll
      for (int i = 0; i < 4; ++i) {
        int r = r_base + quad * 4 + i;
        if (j0 + n16 > r) s0[i] = -INFINITY;
        if (j0 + 16 + n16 > r) s1[i] = -INFINITY;
      }
    }
    // online softmax, per C-layout row
    float p0[4], p1[4];
#pragma unroll
    for (int i = 0; i < 4; ++i) {
      float mt = fmaxf(s0[i], s1[i]);
      mt = fmaxf(mt, __shfl_xor(mt, 1));
      mt = fmaxf(mt, __shfl_xor(mt, 2));
      mt = fmaxf(mt, __shfl_xor(mt, 4));
      mt = fmaxf(mt, __shfl_xor(mt, 8));
      float mn = fmaxf(m_i[i], mt);
      float alpha = __expf(m_i[i] - mn);   // first tile: exp(-inf)=0
      m_i[i] = mn;
      p0[i] = __expf(s0[i] - mn);
      p1[i] = __expf(s1[i] - mn);
      float rs = p0[i] + p1[i];
      rs += __shfl_xor(rs, 1);
      rs += __shfl_xor(rs, 2);
      rs += __shfl_xor(rs, 4);
      rs += __shfl_xor(rs, 8);
      l_i[i] = l_i[i] * alpha + rs;
#pragma unroll
      for (int dt = 0; dt < 8; ++dt) O[dt][i] *= alpha;
    }
    // P: C-layout -> A-layout via per-wave LDS round-trip (no barrier needed)
#pragma unroll
    for (int i = 0; i < 4; ++i) {
      Pst[w][quad * 4 + i][n16] = (__bf16)p0[i];
      Pst[w][quad * 4 + i][n16 + 16] = (__bf16)p1[i];
    }
    bf16x8 pA = *(const bf16x8*)(&Pst[w][n16][quad * 8]);
    // PV: B = V, lane holds d = dt*16 + n16, keys quad*8 + jj
    const __bf16* vb = Vt + j0 + quad * 8;
#pragma unroll
    for (int dt = 0; dt < 8; ++dt) {
      bf16x8 vB = *(const bf16x8*)(vb + (size_t)(dt * 16 + n16) * T);
      O[dt] = __builtin_amdgcn_mfma_f32_16x16x32_bf16(pA, vB, O[dt], 0, 0, 0);
    }
  }
  // epilogue: y = O / l, overwrite q rows in place
#pragma unroll
  for (int i = 0; i < 4; ++i) {
    float inv = 1.0f / l_i[i];
    int r = r_base + quad * 4 + i;
    float* yp = q + (size_t)r * C + h * D + n16;
#pragma unroll
    for (int dt = 0; dt < 8; ++dt) yp[dt * 16] = O[dt][i] * inv;
  }
}

extern "C" void kernel_launch(void* const* d_in, const int* in_sizes, int n_in,
                              void* d_out, int out_size, void* d_ws, size_t ws_size,
                              hipStream_t stream) {
  (void)in_sizes; (void)n_in; (void)out_size; (void)ws_size;
  const float* x    = (const float*)d_in[0];
  const float* Wq   = (const float*)d_in[1];
  const float* Wk   = (const float*)d_in[2];
  const float* Wv   = (const float*)d_in[3];
  const float* Wo   = (const float*)d_in[4];
  const float* cosb = (const float*)d_in[5];
  const float* sinb = (const float*)d_in[6];
  // d_in[7] = mask: unused (causal structure applied exactly)

  // workspace layout (~60 MB)
  float* q_ws = (float*)d_ws;                         // T*C fp32 (q, then y in-place)
  float* k_ws = q_ws + (size_t)T * C;                 // T*KVH*D fp32
  float* v_ws = k_ws + (size_t)T * KVH * D;           // T*KVH*D fp32
  __bf16* khi = (__bf16*)(v_ws + (size_t)T * KVH * D);          // 4 MB
  __bf16* klo = khi + (size_t)KVH * T * D;                      // 4 MB
  __bf16* vt  = klo + (size_t)KVH * T * D;                      // 4 MB

  float* out_y = (float*)d_out;
  float* out_k = out_y + (size_t)T * C;
  float* out_v = out_k + (size_t)KVH * T * D;

  dim3 blk(256);
  // projections (fp32 for now)
  gemm_f32<<<dim3(C / 64, T / 64), blk, 0, stream>>>(x, Wq, q_ws, T, C, C);
  gemm_f32<<<dim3((KVH * D) / 64, T / 64), blk, 0, stream>>>(x, Wk, k_ws, T, KVH * D, C);
  gemm_f32<<<dim3((KVH * D) / 64, T / 64), blk, 0, stream>>>(x, Wv, v_ws, T, KVH * D, C);
  // rope on q and k (in place)
  int rope_total = T * (H + KVH) * (D / 2);
  rope_kernel<<<(rope_total + 255) / 256, blk, 0, stream>>>(q_ws, k_ws, cosb, sinb);
  // conversions + kv outputs
  convert_k<<<(KVH * T * D) / 256, blk, 0, stream>>>(k_ws, out_k, khi, klo);
  convert_v<<<dim3(T / 64, D / 64, KVH), blk, 0, stream>>>(v_ws, out_v, vt);
  // flash attention (writes y over q_ws)
  flash_attn<<<dim3(T / 64, H), blk, 0, stream>>>(q_ws, khi, klo, vt);
  // output projection
  gemm_f32<<<dim3(C / 64, T / 64), blk, 0, stream>>>(q_ws, Wo, out_y, T, C, C);
}